// Round 5
// baseline (659.960 us; speedup 1.0000x reference)
//
#include <hip/hip_runtime.h>
#include <math.h>

#define QL 1024
#define BSZ 4
#define DM 512
#define NH 8
#define DHH 64
#define MEML 1024
#define KL 2048
#define DMLP 2048

typedef __attribute__((ext_vector_type(8))) short bf16x8;
typedef __attribute__((ext_vector_type(4))) float f32x4;

#define MFMA16(A, B, C) __builtin_amdgcn_mfma_f32_16x16x32_bf16((A), (B), (C), 0, 0, 0)
// byte offset into a [rows][64] bf16 tile (row stride 128B), T2 XOR-swizzled
#define SWZB(r, cb) (((r) << 7) + ((cb) ^ (((r) & 7) << 4)))
// byte offset into the [64][128] f32 ring (row stride 512B), same swizzle
#define RINGB(r, c) (((r) << 9) + ((((c) << 2)) ^ (((r) & 7) << 4)))
#define CVT2(dst, lo, hi) \
  asm("v_cvt_pk_bf16_f32 %0, %1, %2" : "=v"(dst) : "v"(lo), "v"(hi))
// async global->LDS, 16B per lane; LDS dest wave-uniform, global addr per-lane
#define GLOAD_LDS(gp, lp) __builtin_amdgcn_global_load_lds( \
    (const __attribute__((address_space(1))) void*)(gp), \
    (__attribute__((address_space(3))) void*)(lp), 16, 0, 0)

// ---------------- split fp32 -> (hi, lo) bf16 ------------------------------
__device__ __forceinline__ void split_bf16(const float4 a, uint2& h, uint2& l) {
  CVT2(h.x, a.x, a.y); CVT2(h.y, a.z, a.w);
  float4 r;
  r.x = a.x - __uint_as_float(h.x << 16);
  r.y = a.y - __uint_as_float(h.x & 0xffff0000u);
  r.z = a.z - __uint_as_float(h.y << 16);
  r.w = a.w - __uint_as_float(h.y & 0xffff0000u);
  CVT2(l.x, r.x, r.y); CVT2(l.y, r.z, r.w);
}

// store into pre-swizzled tiled layout [row/128][c0/64][128][64] (bf16)
__device__ __forceinline__ void store_tiled(char* hiB, char* loB, int KT,
                                            int row, int c0, uint2 h, uint2 l) {
  const size_t off = (((size_t)(row >> 7) * KT + (c0 >> 6)) << 14)
                   + SWZB(row & 127, (c0 & 63) * 2);
  *(uint2*)(hiB + off) = h;
  *(uint2*)(loB + off) = l;
}

// ---------------- fused precvt: all hi/lo splits in one launch -------------
__global__ __launch_bounds__(256)
void precvt_all(const float* __restrict__ mem, const float* __restrict__ inputs,
                const float* __restrict__ r, const float* __restrict__ Wqkv,
                const float* __restrict__ Wr, const float* __restrict__ Wo,
                const float* __restrict__ w1, const float* __restrict__ w2,
                unsigned short* CAThi, unsigned short* CATlo,
                unsigned short* Rhi, unsigned short* Rlo,
                unsigned short* Qhi, unsigned short* Qlo,
                unsigned short* WrHi, unsigned short* WrLo,
                unsigned short* WoHi, unsigned short* WoLo,
                unsigned short* w1Hi, unsigned short* w1Lo,
                unsigned short* w2Hi, unsigned short* w2Lo) {
  const int id = blockIdx.x * 256 + threadIdx.x;
  float4 a; uint2 h, l;
  if (id < 1048576) {            // CAT = [mem; inputs], 8192 x 512
    const int row = id >> 7, c0 = (id & 127) * 4;
    const float* s = (row < 4096) ? mem + (size_t)row * 512
                                  : inputs + (size_t)(row - 4096) * 512;
    a = *(const float4*)(s + c0);
    split_bf16(a, h, l);
    store_tiled((char*)CAThi, (char*)CATlo, 8, row, c0, h, l);
  } else if (id < 1310720) {     // r, 2048 x 512
    const int e = id - 1048576, row = e >> 7, c0 = (e & 127) * 4;
    a = *(const float4*)(r + (size_t)row * 512 + c0);
    split_bf16(a, h, l);
    store_tiled((char*)Rhi, (char*)Rlo, 8, row, c0, h, l);
  } else if (id < 1507328) {     // Wqkv, 1536 x 512
    const int e = id - 1310720, row = e >> 7, c0 = (e & 127) * 4;
    a = *(const float4*)(Wqkv + (size_t)row * 512 + c0);
    split_bf16(a, h, l);
    store_tiled((char*)Qhi, (char*)Qlo, 8, row, c0, h, l);
  } else if (id < 1572864) {     // Wr, 512 x 512
    const int e = id - 1507328, row = e >> 7, c0 = (e & 127) * 4;
    a = *(const float4*)(Wr + (size_t)row * 512 + c0);
    split_bf16(a, h, l);
    store_tiled((char*)WrHi, (char*)WrLo, 8, row, c0, h, l);
  } else if (id < 1638400) {     // Wo, 512 x 512
    const int e = id - 1572864, row = e >> 7, c0 = (e & 127) * 4;
    a = *(const float4*)(Wo + (size_t)row * 512 + c0);
    split_bf16(a, h, l);
    store_tiled((char*)WoHi, (char*)WoLo, 8, row, c0, h, l);
  } else if (id < 1900544) {     // w1, 2048 x 512
    const int e = id - 1638400, row = e >> 7, c0 = (e & 127) * 4;
    a = *(const float4*)(w1 + (size_t)row * 512 + c0);
    split_bf16(a, h, l);
    store_tiled((char*)w1Hi, (char*)w1Lo, 8, row, c0, h, l);
  } else if (id < 2162688) {     // w2, 512 x 2048
    const int e = id - 1900544, row = e >> 9, c0 = (e & 511) * 4;
    a = *(const float4*)(w2 + (size_t)row * 2048 + c0);
    split_bf16(a, h, l);
    store_tiled((char*)w2Hi, (char*)w2Lo, 32, row, c0, h, l);
  }
}

// ---------------- pack K/R (swizzled, for DMA) + V^T (linear, for regs) ----
__global__ __launch_bounds__(256)
void pack_kvr(const float* __restrict__ QKV, const float* __restrict__ RK,
              unsigned short* __restrict__ Kb, unsigned short* __restrict__ Rb,
              unsigned short* __restrict__ Vtb) {
  const int id = blockIdx.x * 256 + threadIdx.x;
  if (id < 1048576) {            // K: [b,h,jt][64 j][64 d] bf16, swizzled
    const int c4 = (id & 15) * 4;
    const int j  = (id >> 4) & 2047;
    const int bhv = id >> 15;
    const int bq = bhv >> 3, hq = bhv & 7;
    const float4 a = *(const float4*)(QKV + ((size_t)j * 4 + bq) * 1536 + 512 + hq * 64 + c4);
    uint2 p; CVT2(p.x, a.x, a.y); CVT2(p.y, a.z, a.w);
    *(uint2*)((char*)Kb + (((size_t)bhv * 32 + (j >> 6)) << 13) + SWZB(j & 63, c4 * 2)) = p;
  } else if (id < 1310720) {     // R: [h,jrt][64 jr][64 d] bf16, swizzled
    const int e = id - 1048576;
    const int c4 = (e & 15) * 4;
    const int jr = (e >> 4) & 2047;
    const int hq = e >> 15;
    const float4 a = *(const float4*)(RK + (size_t)jr * 512 + hq * 64 + c4);
    uint2 p; CVT2(p.x, a.x, a.y); CVT2(p.y, a.z, a.w);
    *(uint2*)((char*)Rb + (((size_t)hq * 32 + (jr >> 6)) << 13) + SWZB(jr & 63, c4 * 2)) = p;
  } else if (id < 1572864) {     // V^T: [b,h,jt][64 d][64 j] bf16, LINEAR rows
    const int e = id - 1310720;
    const int d4 = (e & 15) * 4;
    const int jb = ((e >> 4) & 15) * 4;
    const int jt = (e >> 8) & 31;
    const int bhv = e >> 13;
    const int bq = bhv >> 3, hq = bhv & 7;
    const float* src = QKV + ((size_t)(jt * 64 + jb) * 4 + bq) * 1536 + 1024 + hq * 64 + d4;
    const float4 a0 = *(const float4*)(src);
    const float4 a1 = *(const float4*)(src + 6144);
    const float4 a2 = *(const float4*)(src + 12288);
    const float4 a3 = *(const float4*)(src + 18432);
    char* base = (char*)Vtb + (((size_t)bhv * 32 + jt) << 13);
    uint2 p;
    CVT2(p.x, a0.x, a1.x); CVT2(p.y, a2.x, a3.x);
    *(uint2*)(base + (d4 + 0) * 128 + jb * 2) = p;
    CVT2(p.x, a0.y, a1.y); CVT2(p.y, a2.y, a3.y);
    *(uint2*)(base + (d4 + 1) * 128 + jb * 2) = p;
    CVT2(p.x, a0.z, a1.z); CVT2(p.y, a2.z, a3.z);
    *(uint2*)(base + (d4 + 2) * 128 + jb * 2) = p;
    CVT2(p.x, a0.w, a1.w); CVT2(p.y, a2.w, a3.w);
    *(uint2*)(base + (d4 + 3) * 128 + jb * 2) = p;
  }
}

// ---------------- MFMA GEMM (unchanged from round 4) -----------------------
template<int BM, bool AGLDS, bool BIAS, bool RELU>
__global__ __launch_bounds__(256)
void gemm_nt_mfma(const float* __restrict__ A0, const float* __restrict__ A1, int M0,
                  const unsigned short* __restrict__ AhiT, const unsigned short* __restrict__ AloT,
                  const unsigned short* __restrict__ WhiT, const unsigned short* __restrict__ WloT,
                  const float* __restrict__ bias,
                  float* __restrict__ C, int M, int N, int K) {
  constexpr int MR = 4;
  constexpr int NR = (BM == 128) ? 4 : 2;
  constexpr int AU = BM / 16;
  __shared__ __align__(16) unsigned short Ahi[BM * 64];
  __shared__ __align__(16) unsigned short Alo[BM * 64];
  __shared__ __align__(16) unsigned short Bhi[128 * 64];
  __shared__ __align__(16) unsigned short Blo[128 * 64];

  const int t = threadIdx.x;
  const int w = t >> 6, lane = t & 63;
  const int lq = lane & 15, lg = lane >> 4;
  const int row0 = blockIdx.y * BM, col0 = blockIdx.x * 128;
  const int wrow0 = (BM == 128) ? (w >> 1) * 64 : 0;
  const int wcol0 = (BM == 128) ? (w & 1) * 64 : w * 32;
  const int KT = K >> 6;
  const size_t amt = (size_t)(row0 >> 7) * KT;
  const int asub = (row0 & 127) << 7;
  const size_t bnt = (size_t)(col0 >> 7) * KT;

  float4 paf[AU];
  auto loadA = [&](int k0) {
    if (!AGLDS) {
      #pragma unroll
      for (int it = 0; it < AU; ++it) {
        const int idx = it * 256 + t;
        const int row = idx >> 4, c4 = (idx & 15) * 4;
        const int grow = row0 + row;
        const float* src = (grow < M0) ? (A0 + (size_t)grow * K)
                                       : (A1 + (size_t)(grow - M0) * K);
        paf[it] = *(const float4*)(src + k0 + c4);
      }
    }
  };

  f32x4 acc[MR][NR];
  #pragma unroll
  for (int m = 0; m < MR; ++m)
    #pragma unroll
    for (int n = 0; n < NR; ++n)
      acc[m][n] = (f32x4){0.f, 0.f, 0.f, 0.f};

  loadA(0);
  for (int kt = 0; kt < KT; ++kt) {
    __syncthreads();
    {
      const char* gbh = (const char*)WhiT + ((bnt + kt) << 14);
      const char* gbl = (const char*)WloT + ((bnt + kt) << 14);
      #pragma unroll
      for (int i = 0; i < 4; ++i) {
        const int off = (w * 4 + i) * 1024;
        GLOAD_LDS(gbh + off + lane * 16, (char*)Bhi + off);
        GLOAD_LDS(gbl + off + lane * 16, (char*)Blo + off);
      }
    }
    if (AGLDS) {
      const char* gah = (const char*)AhiT + ((amt + kt) << 14) + asub;
      const char* gal = (const char*)AloT + ((amt + kt) << 14) + asub;
      #pragma unroll
      for (int i = 0; i < BM / 32; ++i) {
        const int off = (w * (BM / 32) + i) * 1024;
        GLOAD_LDS(gah + off + lane * 16, (char*)Ahi + off);
        GLOAD_LDS(gal + off + lane * 16, (char*)Alo + off);
      }
    } else {
      #pragma unroll
      for (int it = 0; it < AU; ++it) {
        const int idx = it * 256 + t;
        const int row = idx >> 4, cb = (idx & 15) * 8;
        uint2 hi, lo;
        split_bf16(paf[it], hi, lo);
        *(uint2*)((char*)Ahi + SWZB(row, cb)) = hi;
        *(uint2*)((char*)Alo + SWZB(row, cb)) = lo;
      }
    }
    __syncthreads();
    if (!AGLDS && kt + 1 < KT) loadA((kt + 1) * 64);
    #pragma unroll
    for (int ks = 0; ks < 2; ++ks) {
      bf16x8 ah[MR], al[MR], bh[NR], bl[NR];
      #pragma unroll
      for (int m = 0; m < MR; ++m) {
        ah[m] = *(const bf16x8*)((const char*)Ahi + SWZB(wrow0 + m * 16 + lq, ks * 64 + lg * 16));
        al[m] = *(const bf16x8*)((const char*)Alo + SWZB(wrow0 + m * 16 + lq, ks * 64 + lg * 16));
      }
      #pragma unroll
      for (int n = 0; n < NR; ++n) {
        bh[n] = *(const bf16x8*)((const char*)Bhi + SWZB(wcol0 + n * 16 + lq, ks * 64 + lg * 16));
        bl[n] = *(const bf16x8*)((const char*)Blo + SWZB(wcol0 + n * 16 + lq, ks * 64 + lg * 16));
      }
      #pragma unroll
      for (int m = 0; m < MR; ++m)
        #pragma unroll
        for (int n = 0; n < NR; ++n) {
          acc[m][n] = MFMA16(ah[m], bh[n], acc[m][n]);
          acc[m][n] = MFMA16(ah[m], bl[n], acc[m][n]);
          acc[m][n] = MFMA16(al[m], bh[n], acc[m][n]);
        }
    }
  }
  #pragma unroll
  for (int n = 0; n < NR; ++n) {
    const int col = col0 + wcol0 + n * 16 + lq;
    const float bv = BIAS ? bias[col] : 0.f;
    #pragma unroll
    for (int m = 0; m < MR; ++m) {
      #pragma unroll
      for (int rg = 0; rg < 4; ++rg) {
        const int row = row0 + wrow0 + m * 16 + lg * 4 + rg;
        float vv = acc[m][n][rg] + bv;
        if (RELU) vv = fmaxf(vv, 0.f);
        C[(size_t)row * N + col] = vv;
      }
    }
  }
}

// ---------------- MFMA attention v3 ----------------
// Block = (64 q-rows, b, h); 4 waves. K/R double-buffered via global_load_lds
// from packed bf16 tiles; V fragments direct-from-global; 1 barrier/tile.
__global__ __launch_bounds__(256)
void attn3_kernel(const float* __restrict__ QKV,
                  const unsigned short* __restrict__ Kb,
                  const unsigned short* __restrict__ Rb,
                  const unsigned short* __restrict__ Vtb,
                  const float* __restrict__ u, const float* __restrict__ v,
                  unsigned short* __restrict__ P, float* __restrict__ INV,
                  float* __restrict__ ATTN) {
  const int b = blockIdx.y;
  const int h = blockIdx.z;
  const int i0 = (((h >> 2) & 1) ? (15 - (int)blockIdx.x) : (int)blockIdx.x) * 64;
  const int t = threadIdx.x;
  const int w = t >> 6;
  const int lane = t & 63;
  const int lq = lane & 15;
  const int lg = lane >> 4;
  const int bh = b * 8 + h;

  __shared__ __align__(16) unsigned short Ks[2][4096];  // K tiles, dbuf, swz
  __shared__ __align__(16) unsigned short Rs[2][4096];  // R tiles, dbuf, swz
  __shared__ __align__(16) unsigned short Es[4096];     // P tile (Qu at prologue)
  __shared__ __align__(16) float Ring[8192];            // BD [i][128] f32 swz

  const int ntiles = i0 / 64 + 17;

  auto dma = [&](int jt, int jrt, int buf) {
    const char* gk = (const char*)Kb + (((size_t)bh * 32 + jt) << 13);
    const char* gr = (const char*)Rb + (((size_t)h * 32 + jrt) << 13);
    const int off = w * 2048;
    GLOAD_LDS(gk + off + lane * 16, (char*)Ks[buf] + off);
    GLOAD_LDS(gk + off + 1024 + lane * 16, (char*)Ks[buf] + off + 1024);
    GLOAD_LDS(gr + off + lane * 16, (char*)Rs[buf] + off);
    GLOAD_LDS(gr + off + 1024 + lane * 16, (char*)Rs[buf] + off + 1024);
  };

  // ---- prologue DMAs: tile 0 -> buf0; prologue R window -> Rs[1] ----
  dma(0, (1024 - i0) >> 6, 0);
  {
    const int jrtp = (960 - i0) >> 6;
    const char* gr = (const char*)Rb + (((size_t)h * 32 + jrtp) << 13);
    const int off = w * 2048;
    GLOAD_LDS(gr + off + lane * 16, (char*)Rs[1] + off);
    GLOAD_LDS(gr + off + 1024 + lane * 16, (char*)Rs[1] + off + 1024);
  }
  // ---- stage Qu -> Es, Qv -> Ks[1] (fp32 reads, fold u/v, cvt) ----
  #pragma unroll
  for (int it = 0; it < 4; ++it) {
    const int idx = it * 256 + t;
    const int row = idx >> 4, c4 = (idx & 15) * 4;
    const float4 q4 = *(const float4*)(QKV + ((size_t)(MEML + i0 + row) * 4 + b) * 1536 + h * 64 + c4);
    const float4 u4 = *(const float4*)(u + h * 64 + c4);
    const float4 v4 = *(const float4*)(v + h * 64 + c4);
    uint2 qp;
    CVT2(qp.x, q4.x + u4.x, q4.y + u4.y); CVT2(qp.y, q4.z + u4.z, q4.w + u4.w);
    *(uint2*)((char*)Es + SWZB(row, c4 * 2)) = qp;
    CVT2(qp.x, q4.x + v4.x, q4.y + v4.y); CVT2(qp.y, q4.z + v4.z, q4.w + v4.w);
    *(uint2*)((char*)Ks[1] + SWZB(row, c4 * 2)) = qp;
  }
  __syncthreads();   // DMAs drained + Q staged

  const bf16x8 qu0 = *(const bf16x8*)((const char*)Es + SWZB(w * 16 + lq, lg * 16));
  const bf16x8 qu1 = *(const bf16x8*)((const char*)Es + SWZB(w * 16 + lq, 64 + lg * 16));
  const bf16x8 qv0 = *(const bf16x8*)((const char*)Ks[1] + SWZB(w * 16 + lq, lg * 16));
  const bf16x8 qv1 = *(const bf16x8*)((const char*)Ks[1] + SWZB(w * 16 + lq, 64 + lg * 16));

  // ---- prologue BD from Rs[1] -> ring cols 64..127 ----
  {
    f32x4 bd[4];
    #pragma unroll
    for (int nj = 0; nj < 4; ++nj) bd[nj] = (f32x4){0.f, 0.f, 0.f, 0.f};
    #pragma unroll
    for (int nj = 0; nj < 4; ++nj) {
      const bf16x8 rf0 = *(const bf16x8*)((const char*)Rs[1] + SWZB(nj * 16 + lq, lg * 16));
      const bf16x8 rf1 = *(const bf16x8*)((const char*)Rs[1] + SWZB(nj * 16 + lq, 64 + lg * 16));
      bd[nj] = MFMA16(qv0, rf0, bd[nj]);
      bd[nj] = MFMA16(qv1, rf1, bd[nj]);
    }
    #pragma unroll
    for (int nj = 0; nj < 4; ++nj) {
      const int jrl = nj * 16 + lq;
      #pragma unroll
      for (int rg = 0; rg < 4; ++rg) {
        const int il = w * 16 + lg * 4 + rg;
        *(float*)((char*)Ring + RINGB(il, 64 + jrl)) = bd[nj][rg];
      }
    }
  }

  f32x4 pv[4];
  #pragma unroll
  for (int nd = 0; nd < 4; ++nd) pv[nd] = (f32x4){0.f, 0.f, 0.f, 0.f};
  float rs[4] = {0.f, 0.f, 0.f, 0.f};

  for (int n = 0; n < ntiles; ++n) {
    const int j0 = n * 64;
    const int cur = n & 1;
    __syncthreads();   // buf[cur] DMA drained; prev readers of buf[cur^1] done
    // ---- V fragments direct from global (L3-resident packed V^T) ----
    const char* gv = (const char*)Vtb + (((size_t)bh * 32 + n) << 13);
    bf16x8 vf0[4], vf1[4];
    #pragma unroll
    for (int nd = 0; nd < 4; ++nd) {
      vf0[nd] = *(const bf16x8*)(gv + (nd * 16 + lq) * 128 + lg * 16);
      vf1[nd] = *(const bf16x8*)(gv + (nd * 16 + lq) * 128 + 64 + lg * 16);
    }
    // ---- issue next tile's DMA into buf^1 (flies during compute) ----
    if (n + 1 < ntiles) {
      int jrt = ((n + 1) * 64 - i0 + 1024) >> 6;
      if (jrt > 31) jrt = 31;   // garbage only feeds masked elems
      dma(n + 1, jrt, cur ^ 1);
    }
    // ---- AC and BD MFMAs from buf[cur] ----
    const char* KsB = (const char*)Ks[cur];
    const char* RsB = (const char*)Rs[cur];
    f32x4 acc[4], bdn[4];
    #pragma unroll
    for (int nj = 0; nj < 4; ++nj) {
      acc[nj] = (f32x4){0.f, 0.f, 0.f, 0.f};
      bdn[nj] = (f32x4){0.f, 0.f, 0.f, 0.f};
    }
    #pragma unroll
    for (int nj = 0; nj < 4; ++nj) {
      const bf16x8 kf0 = *(const bf16x8*)(KsB + SWZB(nj * 16 + lq, lg * 16));
      const bf16x8 rf0 = *(const bf16x8*)(RsB + SWZB(nj * 16 + lq, lg * 16));
      acc[nj] = MFMA16(qu0, kf0, acc[nj]);
      bdn[nj] = MFMA16(qv0, rf0, bdn[nj]);
      const bf16x8 kf1 = *(const bf16x8*)(KsB + SWZB(nj * 16 + lq, 64 + lg * 16));
      const bf16x8 rf1 = *(const bf16x8*)(RsB + SWZB(nj * 16 + lq, 64 + lg * 16));
      acc[nj] = MFMA16(qu1, kf1, acc[nj]);
      bdn[nj] = MFMA16(qv1, rf1, bdn[nj]);
    }
    const int base_cur = cur * 64;
    const int base_prev = 64 - base_cur;
    // ---- ring write (cur half), intra-wave ----
    #pragma unroll
    for (int nj = 0; nj < 4; ++nj) {
      const int jrl = nj * 16 + lq;
      #pragma unroll
      for (int rg = 0; rg < 4; ++rg) {
        const int il = w * 16 + lg * 4 + rg;
        *(float*)((char*)Ring + RINGB(il, base_cur + jrl)) = bdn[nj][rg];
      }
    }
    // ---- scores, exp (mask only on last tile), Es writes (own rows) ----
    const bool lastm = (n == ntiles - 1);
    #pragma unroll
    for (int njp = 0; njp < 2; ++njp) {
      #pragma unroll
      for (int rg = 0; rg < 4; ++rg) {
        const int il = w * 16 + lg * 4 + rg;
        float ee[2];
        #pragma unroll
        for (int q2 = 0; q2 < 2; ++q2) {
          const int nj = njp * 2 + q2;
          const int jl = nj * 16 + lq;
          const int jr_rel = jl - il + 63;
          const float ringv = (jr_rel < 64)
              ? *(const float*)((const char*)Ring + RINGB(il, base_prev + jr_rel))
              : *(const float*)((const char*)Ring + RINGB(il, base_cur + jr_rel - 64));
          const float s = 0.125f * (acc[nj][rg] + ringv);
          float e = __expf(s);
          if (lastm && jl > il) e = 0.f;
          rs[rg] += e;
          ee[q2] = e;
        }
        unsigned int pk2; CVT2(pk2, ee[0], ee[1]);
        const int jlA = (njp * 2) * 16 + lq;
        *(unsigned short*)((char*)Es + SWZB(il, jlA * 2)) = (unsigned short)(pk2 & 0xffffu);
        *(unsigned short*)((char*)Es + SWZB(il, (jlA + 16) * 2)) = (unsigned short)(pk2 >> 16);
      }
    }
    // ---- PV MFMAs (own-wave Es rows x V regs) ----
    {
      const bf16x8 pf0 = *(const bf16x8*)((const char*)Es + SWZB(w * 16 + lq, lg * 16));
      const bf16x8 pf1 = *(const bf16x8*)((const char*)Es + SWZB(w * 16 + lq, 64 + lg * 16));
      #pragma unroll
      for (int nd = 0; nd < 4; ++nd) {
        pv[nd] = MFMA16(pf0, vf0[nd], pv[nd]);
        pv[nd] = MFMA16(pf1, vf1[nd], pv[nd]);
      }
    }
    // ---- per-wave P store (own 16 rows) ----
    #pragma unroll
    for (int it = 0; it < 2; ++it) {
      const int lin = it * 64 + lane;
      const int rr = lin >> 3, c16 = lin & 7;
      const int row = w * 16 + rr;
      const uint4 val = *(const uint4*)((const char*)Es + SWZB(row, c16 * 16));
      *(uint4*)(P + ((size_t)bh * 1024 + i0 + row) * 2048 + j0 + c16 * 8) = val;
    }
  }

  // ---- row sums -> inv; write INV; scale PV; store ATTN ----
  #pragma unroll
  for (int rg = 0; rg < 4; ++rg) {
    #pragma unroll
    for (int m = 1; m < 16; m <<= 1) rs[rg] += __shfl_xor(rs[rg], m, 64);
  }
  float inv[4];
  #pragma unroll
  for (int rg = 0; rg < 4; ++rg) inv[rg] = 1.0f / rs[rg];
  if (lq == 0) {
    #pragma unroll
    for (int rg = 0; rg < 4; ++rg)
      INV[(size_t)bh * 1024 + i0 + w * 16 + lg * 4 + rg] = inv[rg];
  }
  #pragma unroll
  for (int nd = 0; nd < 4; ++nd) {
    #pragma unroll
    for (int rg = 0; rg < 4; ++rg) {
      ATTN[((size_t)(i0 + w * 16 + lg * 4 + rg) * 4 + b) * 512 + h * 64 + nd * 16 + lq] =
          pv[nd][rg] * inv[rg];
    }
  }
}

// ---------------- normalize + transpose P[b,h,i,j](bf16) -> prob[i,j,b,h] --
__global__ __launch_bounds__(256)
void ptrans_kernel(const unsigned short* __restrict__ P, const float* __restrict__ INV,
                   float* __restrict__ prob) {
  const int i  = blockIdx.x;
  const int j0 = blockIdx.y * 64;
  const int t  = threadIdx.x;
  __shared__ float tile[32][65];
  __shared__ float invs[32];
  const bool valid = j0 <= (i & ~63) + MEML;
  if (t < 32) invs[t] = INV[(size_t)t * 1024 + i];
  if (valid) {
    const int bh = t >> 3, part = t & 7;
    const uint4 raw = *(const uint4*)(P + ((size_t)bh * 1024 + i) * 2048 + j0 + part * 8);
    const unsigned int w[4] = {raw.x, raw.y, raw.z, raw.w};
    #pragma unroll
    for (int k = 0; k < 4; ++k) {
      tile[bh][part*8 + 2*k]     = __uint_as_float(w[k] << 16);
      tile[bh][part*8 + 2*k + 1] = __uint_as_float(w[k] & 0xffff0000u);
    }
  }
  __syncthreads();
  #pragma unroll
  for (int it = 0; it < 8; ++it) {
    const int idx = it * 256 + t;
    const int jl = idx >> 5, bh = idx & 31;
    const float val = valid ? tile[bh][jl] * invs[bh] : 0.f;
    prob[((size_t)i * 2048 + j0 + jl) * 32 + bh] = val;
  }
}

// ---------------- Residual + LayerNorm ----------------
__global__ __launch_bounds__(256)
void ln_res_kernel(const float* __restrict__ xa, const float* __restrict__ xb,
                   const float* __restrict__ g, const float* __restrict__ bb,
                   float* __restrict__ y) {
  const int rrow = blockIdx.x;
  const int t = threadIdx.x;
  const size_t base = (size_t)rrow * DM;
  __shared__ float red[256];
  const float a0 = xa[base + t]       + xb[base + t];
  const float a1 = xa[base + t + 256] + xb[base + t + 256];
  red[t] = a0 + a1; __syncthreads();
  for (int s = 128; s > 0; s >>= 1) { if (t < s) red[t] += red[t+s]; __syncthreads(); }
  const float mu = red[0] * (1.0f/512.0f);
  __syncthreads();
  red[t] = a0*a0 + a1*a1; __syncthreads();
  for (int s = 128; s > 0; s >>= 1) { if (t < s) red[t] += red[t+s]; __syncthreads(); }
  const float var = red[0] * (1.0f/512.0f) - mu*mu;
  const float w = rsqrtf(var + 1e-5f);
  y[base + t]       = (a0 - mu) * w * g[t]       + bb[t];
  y[base + t + 256] = (a1 - mu) * w * g[t + 256] + bb[t + 256];
}

extern "C" void kernel_launch(void* const* d_in, const int* in_sizes, int n_in,
                              void* d_out, int out_size, void* d_ws, size_t ws_size,
                              hipStream_t stream) {
  const float* inputs = (const float*)d_in[0];
  const float* r      = (const float*)d_in[1];
  const float* u      = (const float*)d_in[2];
  const float* v      = (const float*)d_in[3];
  const float* mem    = (const float*)d_in[4];
  const float* Wqkv   = (const float*)d_in[6];
  const float* Wr     = (const float*)d_in[7];
  const float* Wo     = (const float*)d_in[8];
  const float* ln1g   = (const float*)d_in[9];
  const float* ln1b   = (const float*)d_in[10];
  const float* w1     = (const float*)d_in[11];
  const float* b1     = (const float*)d_in[12];
  const float* w2     = (const float*)d_in[13];
  const float* b2     = (const float*)d_in[14];
  const float* ln2g   = (const float*)d_in[15];
  const float* ln2b   = (const float*)d_in[16];

  float* out  = (float*)d_out;              // [1024,4,512]
  float* prob = out + (size_t)QL*BSZ*DM;    // [1024,2048,4,8]

  // Workspace (float slots)
  float* ws   = (float*)d_ws;
  unsigned short* P = (unsigned short*)ws;   // [32][1024][2048] bf16
  float* QKV  = ws + 33554432;               // 8192*1536
  float* RK   = QKV + 12582912;              // 2048*512
  float* ATTN = RK + 1048576;                // 4096*512
  float* AO   = ATTN + 2097152;              // 4096*512
  float* Y    = AO + 2097152;                // 4096*512
  float* INV  = Y + 2097152;                 // 32768
  float* HM   = ws;                          // alias P (dead after ptrans)
  float* Z    = ws + 8388608;                // inside P region

  // early tiled hi/lo (alias P region; dead before attn3 writes P)
  unsigned short* CAThiT = (unsigned short*)ws;            // 8192x512
  unsigned short* CATloT = CAThiT + 4194304;
  unsigned short* RhiT   = CATloT + 4194304;               // 2048x512
  unsigned short* RloT   = RhiT + 1048576;
  unsigned short* WqhiT  = RloT + 1048576;                 // 1536x512
  unsigned short* WqloT  = WqhiT + 786432;
  unsigned short* WrhiT  = WqloT + 786432;                 // 512x512
  unsigned short* WrloT  = WrhiT + 262144;
  // late tiled hi/lo (beyond fp32 buffers; never aliased)
  unsigned short* WohiT = (unsigned short*)(ws + 53510144); // 512x512
  unsigned short* WoloT = WohiT + 262144;
  unsigned short* w1hiT = WoloT + 262144;                  // 2048x512
  unsigned short* w1loT = w1hiT + 1048576;
  unsigned short* w2hiT = w1loT + 1048576;                 // 512x2048
  unsigned short* w2loT = w2hiT + 1048576;
  // packed attention operands (after late weights)
  unsigned short* Kb  = (unsigned short*)(ws + 55869440);  // 32*32*4096
  unsigned short* Vtb = Kb + 4194304;
  unsigned short* Rb  = Vtb + 4194304;                     // 8*32*4096

  const dim3 blk256(256);

  precvt_all<<<dim3(8448), blk256, 0, stream>>>(
      mem, inputs, r, Wqkv, Wr, Wo, w1, w2,
      CAThiT, CATloT, RhiT, RloT, WqhiT, WqloT, WrhiT, WrloT,
      WohiT, WoloT, w1hiT, w1loT, w2hiT, w2loT);

  // QKV: [8192,1536] = CAT @ Wqkv^T, K=512
  gemm_nt_mfma<128,true,false,false><<<dim3(12, 64), blk256, 0, stream>>>(
      nullptr, nullptr, 0, CAThiT, CATloT, WqhiT, WqloT, nullptr, QKV, 8192, 1536, 512);
  // RK: [2048,512] = r @ Wr^T, K=512
  gemm_nt_mfma<64,true,false,false><<<dim3(4, 32), blk256, 0, stream>>>(
      nullptr, nullptr, 0, RhiT, RloT, WrhiT, WrloT, nullptr, RK, 2048, 512, 512);
  pack_kvr<<<dim3(6144), blk256, 0, stream>>>(QKV, RK, Kb, Rb, Vtb);
  attn3_kernel<<<dim3(16, BSZ, NH), blk256, 0, stream>>>(
      QKV, Kb, Rb, Vtb, u, v, P, INV, ATTN);
  ptrans_kernel<<<dim3(1024, 32), blk256, 0, stream>>>(P, INV, prob);

  // AO: [4096,512] = ATTN @ Wo^T, K=512
  gemm_nt_mfma<64,false,false,false><<<dim3(4, 64), blk256, 0, stream>>>(
      ATTN, ATTN, 4096, nullptr, nullptr, WohiT, WoloT, nullptr, AO, 4096, 512, 512);
  ln_res_kernel<<<dim3(4096), blk256, 0, stream>>>(inputs, AO, ln1g, ln1b, Y);
  // HM: [4096,2048] = Y @ w1^T + b1, relu, K=512
  gemm_nt_mfma<128,false,true,true><<<dim3(16, 32), blk256, 0, stream>>>(
      Y, Y, 4096, nullptr, nullptr, w1hiT, w1loT, b1, HM, 4096, 2048, 512);
  // Z: [4096,512] = HM @ w2^T + b2, K=2048
  gemm_nt_mfma<64,false,true,false><<<dim3(4, 64), blk256, 0, stream>>>(
      HM, HM, 4096, nullptr, nullptr, w2hiT, w2loT, b2, Z, 4096, 512, 2048);
  ln_res_kernel<<<dim3(4096), blk256, 0, stream>>>(Y, Z, ln2g, ln2b, out);
}

// Round 6
// 656.369 us; speedup vs baseline: 1.0055x; 1.0055x over previous
//
#include <hip/hip_runtime.h>
#include <math.h>

#define QL 1024
#define BSZ 4
#define DM 512
#define NH 8
#define DHH 64
#define MEML 1024
#define KL 2048
#define DMLP 2048

typedef __attribute__((ext_vector_type(8))) short bf16x8;
typedef __attribute__((ext_vector_type(4))) float f32x4;

#define MFMA16(A, B, C) __builtin_amdgcn_mfma_f32_16x16x32_bf16((A), (B), (C), 0, 0, 0)
// byte offset into a [rows][64] bf16 tile (row stride 128B), T2 XOR-swizzled
#define SWZB(r, cb) (((r) << 7) + ((cb) ^ (((r) & 7) << 4)))
// byte offset into the [64][128] f32 ring (row stride 512B), same swizzle
#define RINGB(r, c) (((r) << 9) + ((((c) << 2)) ^ (((r) & 7) << 4)))
#define CVT2(dst, lo, hi) \
  asm("v_cvt_pk_bf16_f32 %0, %1, %2" : "=v"(dst) : "v"(lo), "v"(hi))
// async global->LDS, 16B per lane; LDS dest wave-uniform, global addr per-lane
#define GLOAD_LDS(gp, lp) __builtin_amdgcn_global_load_lds( \
    (const __attribute__((address_space(1))) void*)(gp), \
    (__attribute__((address_space(3))) void*)(lp), 16, 0, 0)

// ---------------- scalar bf16 helpers (same HW instr as pack path) ---------
__device__ __forceinline__ unsigned short bf16_1(float x) {
  unsigned int t; CVT2(t, x, x); return (unsigned short)t;
}
__device__ __forceinline__ void split1(float x, unsigned short& h, unsigned short& l) {
  unsigned int th; CVT2(th, x, x);
  h = (unsigned short)th;
  const float r = x - __uint_as_float(((unsigned int)h) << 16);
  unsigned int tl; CVT2(tl, r, r);
  l = (unsigned short)tl;
}

// ---------------- split fp32 -> (hi, lo) bf16 (vectorized) -----------------
__device__ __forceinline__ void split_bf16(const float4 a, uint2& h, uint2& l) {
  CVT2(h.x, a.x, a.y); CVT2(h.y, a.z, a.w);
  float r;
  float4 rr;
  rr.x = a.x - __uint_as_float(h.x << 16);
  rr.y = a.y - __uint_as_float(h.x & 0xffff0000u);
  rr.z = a.z - __uint_as_float(h.y << 16);
  rr.w = a.w - __uint_as_float(h.y & 0xffff0000u);
  CVT2(l.x, rr.x, rr.y); CVT2(l.y, rr.z, rr.w);
  (void)r;
}

// store into pre-swizzled tiled layout [row/128][c0/64][128][64] (bf16)
__device__ __forceinline__ void store_tiled(char* hiB, char* loB, int KT,
                                            int row, int c0, uint2 h, uint2 l) {
  const size_t off = (((size_t)(row >> 7) * KT + (c0 >> 6)) << 14)
                   + SWZB(row & 127, (c0 & 63) * 2);
  *(uint2*)(hiB + off) = h;
  *(uint2*)(loB + off) = l;
}

// ---------------- fused precvt: all hi/lo splits in one launch -------------
__global__ __launch_bounds__(256)
void precvt_all(const float* __restrict__ mem, const float* __restrict__ inputs,
                const float* __restrict__ r, const float* __restrict__ Wqkv,
                const float* __restrict__ Wr, const float* __restrict__ Wo,
                const float* __restrict__ w1, const float* __restrict__ w2,
                unsigned short* CAThi, unsigned short* CATlo,
                unsigned short* Rhi, unsigned short* Rlo,
                unsigned short* Qhi, unsigned short* Qlo,
                unsigned short* WrHi, unsigned short* WrLo,
                unsigned short* WoHi, unsigned short* WoLo,
                unsigned short* w1Hi, unsigned short* w1Lo,
                unsigned short* w2Hi, unsigned short* w2Lo) {
  const int id = blockIdx.x * 256 + threadIdx.x;
  float4 a; uint2 h, l;
  if (id < 1048576) {            // CAT = [mem; inputs], 8192 x 512
    const int row = id >> 7, c0 = (id & 127) * 4;
    const float* s = (row < 4096) ? mem + (size_t)row * 512
                                  : inputs + (size_t)(row - 4096) * 512;
    a = *(const float4*)(s + c0);
    split_bf16(a, h, l);
    store_tiled((char*)CAThi, (char*)CATlo, 8, row, c0, h, l);
  } else if (id < 1310720) {     // r, 2048 x 512
    const int e = id - 1048576, row = e >> 7, c0 = (e & 127) * 4;
    a = *(const float4*)(r + (size_t)row * 512 + c0);
    split_bf16(a, h, l);
    store_tiled((char*)Rhi, (char*)Rlo, 8, row, c0, h, l);
  } else if (id < 1507328) {     // Wqkv, 1536 x 512
    const int e = id - 1310720, row = e >> 7, c0 = (e & 127) * 4;
    a = *(const float4*)(Wqkv + (size_t)row * 512 + c0);
    split_bf16(a, h, l);
    store_tiled((char*)Qhi, (char*)Qlo, 8, row, c0, h, l);
  } else if (id < 1572864) {     // Wr, 512 x 512
    const int e = id - 1507328, row = e >> 7, c0 = (e & 127) * 4;
    a = *(const float4*)(Wr + (size_t)row * 512 + c0);
    split_bf16(a, h, l);
    store_tiled((char*)WrHi, (char*)WrLo, 8, row, c0, h, l);
  } else if (id < 1638400) {     // Wo, 512 x 512
    const int e = id - 1572864, row = e >> 7, c0 = (e & 127) * 4;
    a = *(const float4*)(Wo + (size_t)row * 512 + c0);
    split_bf16(a, h, l);
    store_tiled((char*)WoHi, (char*)WoLo, 8, row, c0, h, l);
  } else if (id < 1900544) {     // w1, 2048 x 512
    const int e = id - 1638400, row = e >> 7, c0 = (e & 127) * 4;
    a = *(const float4*)(w1 + (size_t)row * 512 + c0);
    split_bf16(a, h, l);
    store_tiled((char*)w1Hi, (char*)w1Lo, 8, row, c0, h, l);
  } else if (id < 2162688) {     // w2, 512 x 2048
    const int e = id - 1900544, row = e >> 9, c0 = (e & 511) * 4;
    a = *(const float4*)(w2 + (size_t)row * 2048 + c0);
    split_bf16(a, h, l);
    store_tiled((char*)w2Hi, (char*)w2Lo, 32, row, c0, h, l);
  }
}

// ---------------- MFMA GEMM: C[M,N] = A[M,K] @ W[N,K]^T --------------------
// Both operands via global_load_lds from pre-split tiled hi/lo bf16.
// EPI 0: fp32 C (+bias,+relu).  EPI 1: QKV special (Q fp32 to C[.,512],
//   K packed->X1, V^T packed->X2).  EPI 2: R packed->X1.
//   EPI 3: hi/lo tiled (X1=hi, X2=lo, consumer KT = KTC) (+bias,+relu).
template<int BM, int EPI, bool BIAS, bool RELU>
__global__ __launch_bounds__(256)
void gemm_nt_mfma(const unsigned short* __restrict__ AhiT, const unsigned short* __restrict__ AloT,
                  const unsigned short* __restrict__ WhiT, const unsigned short* __restrict__ WloT,
                  const float* __restrict__ bias,
                  float* __restrict__ C,
                  unsigned short* __restrict__ X1, unsigned short* __restrict__ X2,
                  int N, int K, int KTC) {
  constexpr int MR = 4;
  constexpr int NR = (BM == 128) ? 4 : 2;
  __shared__ __align__(16) unsigned short Ahi[BM * 64];
  __shared__ __align__(16) unsigned short Alo[BM * 64];
  __shared__ __align__(16) unsigned short Bhi[128 * 64];
  __shared__ __align__(16) unsigned short Blo[128 * 64];

  const int t = threadIdx.x;
  const int w = t >> 6, lane = t & 63;
  const int lq = lane & 15, lg = lane >> 4;
  const int row0 = blockIdx.y * BM, col0 = blockIdx.x * 128;
  const int wrow0 = (BM == 128) ? (w >> 1) * 64 : 0;
  const int wcol0 = (BM == 128) ? (w & 1) * 64 : w * 32;
  const int KT = K >> 6;
  const size_t amt = (size_t)(row0 >> 7) * KT;
  const int asub = (row0 & 127) << 7;
  const size_t bnt = (size_t)(col0 >> 7) * KT;

  f32x4 acc[MR][NR];
  #pragma unroll
  for (int m = 0; m < MR; ++m)
    #pragma unroll
    for (int n = 0; n < NR; ++n)
      acc[m][n] = (f32x4){0.f, 0.f, 0.f, 0.f};

  for (int kt = 0; kt < KT; ++kt) {
    __syncthreads();   // prev MFMA done with LDS
    {
      const char* gbh = (const char*)WhiT + ((bnt + kt) << 14);
      const char* gbl = (const char*)WloT + ((bnt + kt) << 14);
      #pragma unroll
      for (int i = 0; i < 4; ++i) {
        const int off = (w * 4 + i) * 1024;
        GLOAD_LDS(gbh + off + lane * 16, (char*)Bhi + off);
        GLOAD_LDS(gbl + off + lane * 16, (char*)Blo + off);
      }
    }
    {
      const char* gah = (const char*)AhiT + ((amt + kt) << 14) + asub;
      const char* gal = (const char*)AloT + ((amt + kt) << 14) + asub;
      #pragma unroll
      for (int i = 0; i < BM / 32; ++i) {
        const int off = (w * (BM / 32) + i) * 1024;
        GLOAD_LDS(gah + off + lane * 16, (char*)Ahi + off);
        GLOAD_LDS(gal + off + lane * 16, (char*)Alo + off);
      }
    }
    __syncthreads();   // vmcnt(0) drain: all LDS ready
    #pragma unroll
    for (int ks = 0; ks < 2; ++ks) {
      bf16x8 ah[MR], al[MR], bh[NR], bl[NR];
      #pragma unroll
      for (int m = 0; m < MR; ++m) {
        ah[m] = *(const bf16x8*)((const char*)Ahi + SWZB(wrow0 + m * 16 + lq, ks * 64 + lg * 16));
        al[m] = *(const bf16x8*)((const char*)Alo + SWZB(wrow0 + m * 16 + lq, ks * 64 + lg * 16));
      }
      #pragma unroll
      for (int n = 0; n < NR; ++n) {
        bh[n] = *(const bf16x8*)((const char*)Bhi + SWZB(wcol0 + n * 16 + lq, ks * 64 + lg * 16));
        bl[n] = *(const bf16x8*)((const char*)Blo + SWZB(wcol0 + n * 16 + lq, ks * 64 + lg * 16));
      }
      #pragma unroll
      for (int m = 0; m < MR; ++m)
        #pragma unroll
        for (int n = 0; n < NR; ++n) {
          acc[m][n] = MFMA16(ah[m], bh[n], acc[m][n]);
          acc[m][n] = MFMA16(ah[m], bl[n], acc[m][n]);
          acc[m][n] = MFMA16(al[m], bh[n], acc[m][n]);
        }
    }
  }
  // ---- epilogue ----
  #pragma unroll
  for (int n = 0; n < NR; ++n) {
    const int col = col0 + wcol0 + n * 16 + lq;
    const float bv = BIAS ? bias[col] : 0.f;
    #pragma unroll
    for (int m = 0; m < MR; ++m) {
      #pragma unroll
      for (int rg = 0; rg < 4; ++rg) {
        const int row = row0 + wrow0 + m * 16 + lg * 4 + rg;
        float vv = acc[m][n][rg] + bv;
        if (RELU) vv = fmaxf(vv, 0.f);
        if constexpr (EPI == 0) {
          C[(size_t)row * N + col] = vv;
        } else if constexpr (EPI == 1) {
          const int j = row >> 2, b = row & 3;
          if (col0 < 512) {                 // Q: fp32 compact
            C[(size_t)row * 512 + col] = vv;
          } else if (col0 < 1024) {         // K packed [b,h,jt][j][d] swz
            const int hh = (col - 512) >> 6, d = (col - 512) & 63;
            const size_t off = (((size_t)((b * 8 + hh) * 32 + (j >> 6))) << 13)
                             + SWZB(j & 63, d * 2);
            *(unsigned short*)((char*)X1 + off) = bf16_1(vv);
          } else {                          // V^T packed [b,h,jt][d][j] linear
            const int hh = (col - 1024) >> 6, d = (col - 1024) & 63;
            const size_t off = (((size_t)((b * 8 + hh) * 32 + (j >> 6))) << 13)
                             + d * 128 + (j & 63) * 2;
            *(unsigned short*)((char*)X2 + off) = bf16_1(vv);
          }
        } else if constexpr (EPI == 2) {    // R packed [h,jrt][jr][d] swz
          const int hh = col >> 6, d = col & 63;
          const size_t off = (((size_t)(hh * 32 + (row >> 6))) << 13)
                           + SWZB(row & 63, d * 2);
          *(unsigned short*)((char*)X1 + off) = bf16_1(vv);
        } else {                            // EPI 3: hi/lo tiled for next gemm
          unsigned short hh, ll;
          split1(vv, hh, ll);
          const size_t off = (((size_t)(row >> 7) * KTC + (col >> 6)) << 14)
                           + SWZB(row & 127, (col & 63) * 2);
          *(unsigned short*)((char*)X1 + off) = hh;
          *(unsigned short*)((char*)X2 + off) = ll;
        }
      }
    }
  }
}

// ---------------- MFMA attention v3 ----------------
// Block = (64 q-rows, b, h); 4 waves. K/R double-buffered via global_load_lds
// from packed bf16 tiles; V fragments direct-from-global; 1 barrier/tile.
// Epilogue writes ATTN as hi/lo tiled bf16 (Wo gemm consumes via DMA).
__global__ __launch_bounds__(256)
void attn3_kernel(const float* __restrict__ Qbuf,
                  const unsigned short* __restrict__ Kb,
                  const unsigned short* __restrict__ Rb,
                  const unsigned short* __restrict__ Vtb,
                  const float* __restrict__ u, const float* __restrict__ v,
                  unsigned short* __restrict__ P, float* __restrict__ INV,
                  unsigned short* __restrict__ AThiT, unsigned short* __restrict__ ATloT) {
  const int b = blockIdx.y;
  const int h = blockIdx.z;
  const int i0 = (((h >> 2) & 1) ? (15 - (int)blockIdx.x) : (int)blockIdx.x) * 64;
  const int t = threadIdx.x;
  const int w = t >> 6;
  const int lane = t & 63;
  const int lq = lane & 15;
  const int lg = lane >> 4;
  const int bh = b * 8 + h;

  __shared__ __align__(16) unsigned short Ks[2][4096];  // K tiles, dbuf, swz
  __shared__ __align__(16) unsigned short Rs[2][4096];  // R tiles, dbuf, swz
  __shared__ __align__(16) unsigned short Es[4096];     // P tile (Qu at prologue)
  __shared__ __align__(16) float Ring[8192];            // BD [i][128] f32 swz

  const int ntiles = i0 / 64 + 17;

  auto dma = [&](int jt, int jrt, int buf) {
    const char* gk = (const char*)Kb + (((size_t)bh * 32 + jt) << 13);
    const char* gr = (const char*)Rb + (((size_t)h * 32 + jrt) << 13);
    const int off = w * 2048;
    GLOAD_LDS(gk + off + lane * 16, (char*)Ks[buf] + off);
    GLOAD_LDS(gk + off + 1024 + lane * 16, (char*)Ks[buf] + off + 1024);
    GLOAD_LDS(gr + off + lane * 16, (char*)Rs[buf] + off);
    GLOAD_LDS(gr + off + 1024 + lane * 16, (char*)Rs[buf] + off + 1024);
  };

  // ---- prologue DMAs: tile 0 -> buf0; prologue R window -> Rs[1] ----
  dma(0, (1024 - i0) >> 6, 0);
  {
    const int jrtp = (960 - i0) >> 6;
    const char* gr = (const char*)Rb + (((size_t)h * 32 + jrtp) << 13);
    const int off = w * 2048;
    GLOAD_LDS(gr + off + lane * 16, (char*)Rs[1] + off);
    GLOAD_LDS(gr + off + 1024 + lane * 16, (char*)Rs[1] + off + 1024);
  }
  // ---- stage Qu -> Es, Qv -> Ks[1] (fp32 reads, fold u/v, cvt) ----
  #pragma unroll
  for (int it = 0; it < 4; ++it) {
    const int idx = it * 256 + t;
    const int row = idx >> 4, c4 = (idx & 15) * 4;
    const float4 q4 = *(const float4*)(Qbuf + ((size_t)(MEML + i0 + row) * 4 + b) * 512 + h * 64 + c4);
    const float4 u4 = *(const float4*)(u + h * 64 + c4);
    const float4 v4 = *(const float4*)(v + h * 64 + c4);
    uint2 qp;
    CVT2(qp.x, q4.x + u4.x, q4.y + u4.y); CVT2(qp.y, q4.z + u4.z, q4.w + u4.w);
    *(uint2*)((char*)Es + SWZB(row, c4 * 2)) = qp;
    CVT2(qp.x, q4.x + v4.x, q4.y + v4.y); CVT2(qp.y, q4.z + v4.z, q4.w + v4.w);
    *(uint2*)((char*)Ks[1] + SWZB(row, c4 * 2)) = qp;
  }
  __syncthreads();   // DMAs drained + Q staged

  const bf16x8 qu0 = *(const bf16x8*)((const char*)Es + SWZB(w * 16 + lq, lg * 16));
  const bf16x8 qu1 = *(const bf16x8*)((const char*)Es + SWZB(w * 16 + lq, 64 + lg * 16));
  const bf16x8 qv0 = *(const bf16x8*)((const char*)Ks[1] + SWZB(w * 16 + lq, lg * 16));
  const bf16x8 qv1 = *(const bf16x8*)((const char*)Ks[1] + SWZB(w * 16 + lq, 64 + lg * 16));

  // ---- prologue BD from Rs[1] -> ring cols 64..127 ----
  {
    f32x4 bd[4];
    #pragma unroll
    for (int nj = 0; nj < 4; ++nj) bd[nj] = (f32x4){0.f, 0.f, 0.f, 0.f};
    #pragma unroll
    for (int nj = 0; nj < 4; ++nj) {
      const bf16x8 rf0 = *(const bf16x8*)((const char*)Rs[1] + SWZB(nj * 16 + lq, lg * 16));
      const bf16x8 rf1 = *(const bf16x8*)((const char*)Rs[1] + SWZB(nj * 16 + lq, 64 + lg * 16));
      bd[nj] = MFMA16(qv0, rf0, bd[nj]);
      bd[nj] = MFMA16(qv1, rf1, bd[nj]);
    }
    #pragma unroll
    for (int nj = 0; nj < 4; ++nj) {
      const int jrl = nj * 16 + lq;
      #pragma unroll
      for (int rg = 0; rg < 4; ++rg) {
        const int il = w * 16 + lg * 4 + rg;
        *(float*)((char*)Ring + RINGB(il, 64 + jrl)) = bd[nj][rg];
      }
    }
  }

  f32x4 pv[4];
  #pragma unroll
  for (int nd = 0; nd < 4; ++nd) pv[nd] = (f32x4){0.f, 0.f, 0.f, 0.f};
  float rs[4] = {0.f, 0.f, 0.f, 0.f};

  for (int n = 0; n < ntiles; ++n) {
    const int j0 = n * 64;
    const int cur = n & 1;
    __syncthreads();   // buf[cur] DMA drained; prev readers of buf[cur^1] done
    // ---- V fragments direct from global (L3-resident packed V^T) ----
    const char* gv = (const char*)Vtb + (((size_t)bh * 32 + n) << 13);
    bf16x8 vf0[4], vf1[4];
    #pragma unroll
    for (int nd = 0; nd < 4; ++nd) {
      vf0[nd] = *(const bf16x8*)(gv + (nd * 16 + lq) * 128 + lg * 16);
      vf1[nd] = *(const bf16x8*)(gv + (nd * 16 + lq) * 128 + 64 + lg * 16);
    }
    // ---- issue next tile's DMA into buf^1 (flies during compute) ----
    if (n + 1 < ntiles) {
      int jrt = ((n + 1) * 64 - i0 + 1024) >> 6;
      if (jrt > 31) jrt = 31;   // garbage only feeds masked elems
      dma(n + 1, jrt, cur ^ 1);
    }
    // ---- AC and BD MFMAs from buf[cur] ----
    const char* KsB = (const char*)Ks[cur];
    const char* RsB = (const char*)Rs[cur];
    f32x4 acc[4], bdn[4];
    #pragma unroll
    for (int nj = 0; nj < 4; ++nj) {
      acc[nj] = (f32x4){0.f, 0.f, 0.f, 0.f};
      bdn[nj] = (f32x4){0.f, 0.f, 0.f, 0.f};
    }
    #pragma unroll
    for (int nj = 0; nj < 4; ++nj) {
      const bf16x8 kf0 = *(const bf16x8*)(KsB + SWZB(nj * 16 + lq, lg * 16));
      const bf16x8 rf0 = *(const bf16x8*)(RsB + SWZB(nj * 16 + lq, lg * 16));
      acc[nj] = MFMA16(qu0, kf0, acc[nj]);
      bdn[nj] = MFMA16(qv0, rf0, bdn[nj]);
      const bf16x8 kf1 = *(const bf16x8*)(KsB + SWZB(nj * 16 + lq, 64 + lg * 16));
      const bf16x8 rf1 = *(const bf16x8*)(RsB + SWZB(nj * 16 + lq, 64 + lg * 16));
      acc[nj] = MFMA16(qu1, kf1, acc[nj]);
      bdn[nj] = MFMA16(qv1, rf1, bdn[nj]);
    }
    const int base_cur = cur * 64;
    const int base_prev = 64 - base_cur;
    // ---- ring write (cur half), intra-wave ----
    #pragma unroll
    for (int nj = 0; nj < 4; ++nj) {
      const int jrl = nj * 16 + lq;
      #pragma unroll
      for (int rg = 0; rg < 4; ++rg) {
        const int il = w * 16 + lg * 4 + rg;
        *(float*)((char*)Ring + RINGB(il, base_cur + jrl)) = bdn[nj][rg];
      }
    }
    // ---- scores, exp (mask only on last tile), Es writes (own rows) ----
    const bool lastm = (n == ntiles - 1);
    #pragma unroll
    for (int njp = 0; njp < 2; ++njp) {
      #pragma unroll
      for (int rg = 0; rg < 4; ++rg) {
        const int il = w * 16 + lg * 4 + rg;
        float ee[2];
        #pragma unroll
        for (int q2 = 0; q2 < 2; ++q2) {
          const int nj = njp * 2 + q2;
          const int jl = nj * 16 + lq;
          const int jr_rel = jl - il + 63;
          const float ringv = (jr_rel < 64)
              ? *(const float*)((const char*)Ring + RINGB(il, base_prev + jr_rel))
              : *(const float*)((const char*)Ring + RINGB(il, base_cur + jr_rel - 64));
          const float s = 0.125f * (acc[nj][rg] + ringv);
          float e = __expf(s);
          if (lastm && jl > il) e = 0.f;
          rs[rg] += e;
          ee[q2] = e;
        }
        unsigned int pk2; CVT2(pk2, ee[0], ee[1]);
        const int jlA = (njp * 2) * 16 + lq;
        *(unsigned short*)((char*)Es + SWZB(il, jlA * 2)) = (unsigned short)(pk2 & 0xffffu);
        *(unsigned short*)((char*)Es + SWZB(il, (jlA + 16) * 2)) = (unsigned short)(pk2 >> 16);
      }
    }
    // ---- PV MFMAs (own-wave Es rows x V regs) ----
    {
      const bf16x8 pf0 = *(const bf16x8*)((const char*)Es + SWZB(w * 16 + lq, lg * 16));
      const bf16x8 pf1 = *(const bf16x8*)((const char*)Es + SWZB(w * 16 + lq, 64 + lg * 16));
      #pragma unroll
      for (int nd = 0; nd < 4; ++nd) {
        pv[nd] = MFMA16(pf0, vf0[nd], pv[nd]);
        pv[nd] = MFMA16(pf1, vf1[nd], pv[nd]);
      }
    }
    // ---- per-wave P store (own 16 rows) ----
    #pragma unroll
    for (int it = 0; it < 2; ++it) {
      const int lin = it * 64 + lane;
      const int rr = lin >> 3, c16 = lin & 7;
      const int row = w * 16 + rr;
      const uint4 val = *(const uint4*)((const char*)Es + SWZB(row, c16 * 16));
      *(uint4*)(P + ((size_t)bh * 1024 + i0 + row) * 2048 + j0 + c16 * 8) = val;
    }
  }

  // ---- row sums -> inv; write INV; scale PV; store ATTN hi/lo tiled ----
  #pragma unroll
  for (int rg = 0; rg < 4; ++rg) {
    #pragma unroll
    for (int m = 1; m < 16; m <<= 1) rs[rg] += __shfl_xor(rs[rg], m, 64);
  }
  float inv[4];
  #pragma unroll
  for (int rg = 0; rg < 4; ++rg) inv[rg] = 1.0f / rs[rg];
  if (lq == 0) {
    #pragma unroll
    for (int rg = 0; rg < 4; ++rg)
      INV[(size_t)bh * 1024 + i0 + w * 16 + lg * 4 + rg] = inv[rg];
  }
  #pragma unroll
  for (int nd = 0; nd < 4; ++nd) {
    const int col = h * 64 + nd * 16 + lq;
    #pragma unroll
    for (int rg = 0; rg < 4; ++rg) {
      const int row = (i0 + w * 16 + lg * 4 + rg) * 4 + b;
      unsigned short hh, ll;
      split1(pv[nd][rg] * inv[rg], hh, ll);
      const size_t off = (((size_t)(row >> 7) * 8 + (col >> 6)) << 14)
                       + SWZB(row & 127, (col & 63) * 2);
      *(unsigned short*)((char*)AThiT + off) = hh;
      *(unsigned short*)((char*)ATloT + off) = ll;
    }
  }
}

// ---------------- normalize + transpose P[b,h,i,j](bf16) -> prob[i,j,b,h] --
__global__ __launch_bounds__(256)
void ptrans_kernel(const unsigned short* __restrict__ P, const float* __restrict__ INV,
                   float* __restrict__ prob) {
  const int i  = blockIdx.x;
  const int j0 = blockIdx.y * 64;
  const int t  = threadIdx.x;
  __shared__ float tile[32][65];
  __shared__ float invs[32];
  const bool valid = j0 <= (i & ~63) + MEML;
  if (t < 32) invs[t] = INV[(size_t)t * 1024 + i];
  if (valid) {
    const int bh = t >> 3, part = t & 7;
    const uint4 raw = *(const uint4*)(P + ((size_t)bh * 1024 + i) * 2048 + j0 + part * 8);
    const unsigned int w[4] = {raw.x, raw.y, raw.z, raw.w};
    #pragma unroll
    for (int k = 0; k < 4; ++k) {
      tile[bh][part*8 + 2*k]     = __uint_as_float(w[k] << 16);
      tile[bh][part*8 + 2*k + 1] = __uint_as_float(w[k] & 0xffff0000u);
    }
  }
  __syncthreads();
  #pragma unroll
  for (int it = 0; it < 8; ++it) {
    const int idx = it * 256 + t;
    const int jl = idx >> 5, bh = idx & 31;
    const float val = valid ? tile[bh][jl] * invs[bh] : 0.f;
    prob[((size_t)i * 2048 + j0 + jl) * 32 + bh] = val;
  }
}

// ---------------- Residual + LayerNorm (optional hi/lo tiled side-output) --
template<bool SPLIT>
__global__ __launch_bounds__(256)
void ln_res_kernel(const float* __restrict__ xa, const float* __restrict__ xb,
                   const float* __restrict__ g, const float* __restrict__ bb,
                   float* __restrict__ y,
                   unsigned short* __restrict__ YhiT, unsigned short* __restrict__ YloT) {
  const int rrow = blockIdx.x;
  const int t = threadIdx.x;
  const size_t base = (size_t)rrow * DM;
  __shared__ float red[256];
  const float a0 = xa[base + t]       + xb[base + t];
  const float a1 = xa[base + t + 256] + xb[base + t + 256];
  red[t] = a0 + a1; __syncthreads();
  for (int s = 128; s > 0; s >>= 1) { if (t < s) red[t] += red[t+s]; __syncthreads(); }
  const float mu = red[0] * (1.0f/512.0f);
  __syncthreads();
  red[t] = a0*a0 + a1*a1; __syncthreads();
  for (int s = 128; s > 0; s >>= 1) { if (t < s) red[t] += red[t+s]; __syncthreads(); }
  const float var = red[0] * (1.0f/512.0f) - mu*mu;
  const float w = rsqrtf(var + 1e-5f);
  const float y0 = (a0 - mu) * w * g[t]       + bb[t];
  const float y1 = (a1 - mu) * w * g[t + 256] + bb[t + 256];
  y[base + t]       = y0;
  y[base + t + 256] = y1;
  if (SPLIT) {
    unsigned short hh, ll;
    split1(y0, hh, ll);
    size_t off = (((size_t)(rrow >> 7) * 8 + (t >> 6)) << 14)
               + SWZB(rrow & 127, (t & 63) * 2);
    *(unsigned short*)((char*)YhiT + off) = hh;
    *(unsigned short*)((char*)YloT + off) = ll;
    split1(y1, hh, ll);
    const int t2 = t + 256;
    off = (((size_t)(rrow >> 7) * 8 + (t2 >> 6)) << 14)
        + SWZB(rrow & 127, (t2 & 63) * 2);
    *(unsigned short*)((char*)YhiT + off) = hh;
    *(unsigned short*)((char*)YloT + off) = ll;
  }
}

extern "C" void kernel_launch(void* const* d_in, const int* in_sizes, int n_in,
                              void* d_out, int out_size, void* d_ws, size_t ws_size,
                              hipStream_t stream) {
  const float* inputs = (const float*)d_in[0];
  const float* r      = (const float*)d_in[1];
  const float* u      = (const float*)d_in[2];
  const float* v      = (const float*)d_in[3];
  const float* mem    = (const float*)d_in[4];
  const float* Wqkv   = (const float*)d_in[6];
  const float* Wr     = (const float*)d_in[7];
  const float* Wo     = (const float*)d_in[8];
  const float* ln1g   = (const float*)d_in[9];
  const float* ln1b   = (const float*)d_in[10];
  const float* w1     = (const float*)d_in[11];
  const float* b1     = (const float*)d_in[12];
  const float* w2     = (const float*)d_in[13];
  const float* b2     = (const float*)d_in[14];
  const float* ln2g   = (const float*)d_in[15];
  const float* ln2b   = (const float*)d_in[16];

  float* out  = (float*)d_out;              // [1024,4,512]
  float* prob = out + (size_t)QL*BSZ*DM;    // [1024,2048,4,8]

  // Workspace (float slots)
  float* ws   = (float*)d_ws;
  unsigned short* P = (unsigned short*)ws;   // [32][1024][2048] bf16 = 33.55M fl

  // early precvt operands (ushort units, alias P; dead before attn writes P)
  unsigned short* CAThiT = (unsigned short*)ws;            // 8192x512
  unsigned short* CATloT = CAThiT + 4194304;
  unsigned short* RinhiT = CATloT + 4194304;               // 2048x512
  unsigned short* RinloT = RinhiT + 1048576;
  unsigned short* WqhiT  = RinloT + 1048576;               // 1536x512
  unsigned short* WqloT  = WqhiT + 786432;
  unsigned short* WrhiT  = WqloT + 786432;                 // 512x512
  unsigned short* WrloT  = WrhiT + 262144;
  // HM hi/lo tiled (alias P; written after ptrans)
  unsigned short* HMhiT = (unsigned short*)ws;             // 4096x2048
  unsigned short* HMloT = HMhiT + 8388608;
  float* Z = ws + 8388608;                                 // fp32, after HM lo

  float* Qbuf = ws + 33554432;               // [8192][512] fp32
  float* AO   = Qbuf + 4194304;              // 4096x512 fp32
  float* Y    = AO + 2097152;                // 4096x512 fp32
  float* INV  = Y + 2097152;                 // 32768
  unsigned short* AThiT = (unsigned short*)(INV + 32768);  // 4096x512
  unsigned short* ATloT = AThiT + 2097152;
  unsigned short* YhiT  = ATloT + 2097152;                 // 4096x512
  unsigned short* YloT  = YhiT + 2097152;
  unsigned short* WohiT = YloT + 2097152;                  // 512x512
  unsigned short* WoloT = WohiT + 262144;
  unsigned short* w1hiT = WoloT + 262144;                  // 2048x512
  unsigned short* w1loT = w1hiT + 1048576;
  unsigned short* w2hiT = w1loT + 1048576;                 // 512x2048
  unsigned short* w2loT = w2hiT + 1048576;
  unsigned short* Kb    = w2loT + 1048576;                 // [32][32][64][64]
  unsigned short* Vtb   = Kb + 4194304;                    // [32][32][64][64]
  unsigned short* Rb    = Vtb + 4194304;                   // [8][32][64][64]

  const dim3 blk256(256);

  precvt_all<<<dim3(8448), blk256, 0, stream>>>(
      mem, inputs, r, Wqkv, Wr, Wo, w1, w2,
      CAThiT, CATloT, RinhiT, RinloT, WqhiT, WqloT, WrhiT, WrloT,
      WohiT, WoloT, w1hiT, w1loT, w2hiT, w2loT);

  // QKV: [8192,1536] = CAT @ Wqkv^T; Q->fp32 Qbuf, K/V->packed
  gemm_nt_mfma<128,1,false,false><<<dim3(12, 64), blk256, 0, stream>>>(
      CAThiT, CATloT, WqhiT, WqloT, nullptr, Qbuf, Kb, Vtb, 1536, 512, 0);
  // RK: [2048,512] = r @ Wr^T -> R packed
  gemm_nt_mfma<64,2,false,false><<<dim3(4, 32), blk256, 0, stream>>>(
      RinhiT, RinloT, WrhiT, WrloT, nullptr, nullptr, Rb, nullptr, 512, 512, 0);
  attn3_kernel<<<dim3(16, BSZ, NH), blk256, 0, stream>>>(
      Qbuf, Kb, Rb, Vtb, u, v, P, INV, AThiT, ATloT);
  ptrans_kernel<<<dim3(1024, 32), blk256, 0, stream>>>(P, INV, prob);

  // AO: [4096,512] = ATTN @ Wo^T (fp32 out)
  gemm_nt_mfma<64,0,false,false><<<dim3(4, 64), blk256, 0, stream>>>(
      AThiT, ATloT, WohiT, WoloT, nullptr, AO, nullptr, nullptr, 512, 512, 0);
  ln_res_kernel<true><<<dim3(4096), blk256, 0, stream>>>(
      inputs, AO, ln1g, ln1b, Y, YhiT, YloT);
  // HM: [4096,2048] = relu(Y @ w1^T + b1) -> hi/lo tiled (consumer KT=32)
  gemm_nt_mfma<128,3,true,true><<<dim3(16, 32), blk256, 0, stream>>>(
      YhiT, YloT, w1hiT, w1loT, b1, nullptr, HMhiT, HMloT, 2048, 512, 32);
  // Z: [4096,512] = HM @ w2^T + b2 (fp32 out)
  gemm_nt_mfma<64,0,true,false><<<dim3(4, 64), blk256, 0, stream>>>(
      HMhiT, HMloT, w2hiT, w2loT, b2, Z, nullptr, nullptr, 512, 2048, 0);
  ln_res_kernel<false><<<dim3(4096), blk256, 0, stream>>>(
      Y, Z, ln2g, ln2b, out, nullptr, nullptr);
}